// Round 14
// baseline (167.083 us; speedup 1.0000x reference)
//
#include <hip/hip_runtime.h>

// Problem constants
#define BB 64
#define II 1152
#define OO 32
#define DD 8
#define HH 16
#define BOH (BB * OO * HH)    // 32768
#define WTILE (OO * DD * HH)  // 4096 floats per i

// Producer / fallback decomposition (R5-exact): NIC * IC == II, 512 blocks.
#define IC   9
#define NIC  128
#define NBB  16    // b per block
#define NBG  4     // b-groups
#define NJB  4     // b per thread

// Fast-pass decomposition (R13-proven): grid (NRNG, BB) = 2048 blocks; block
// owns (i-range of 36, one b); wave q handles a 9-i subgroup (register
// prefetch + 9 independent softmax chains); 4-wave LDS tree -> 32-chunk slab.
// R14: each fast pass ALSO reduces the previous slab for its b in-prologue,
// eliminating 2 reduce dispatches (gap ~6 us each when kernels are short).
#define NRNG 32
#define ICR  (II / NRNG)   // 36

typedef _Float16 half8 __attribute__((ext_vector_type(8)));

// u_hat element count (fp16): 75.5 MB
#define UHN ((size_t)BB * II * OO * HH)

// ---------------------------------------------------------------------------
// DPP add helper (ctrl must be an ICE -> template param).
// ---------------------------------------------------------------------------
template<int CTRL>
__device__ __forceinline__ float dpp_add(float x)
{
    return x + __int_as_float(__builtin_amdgcn_update_dpp(
            0, __float_as_int(x), CTRL, 0xF, 0xF, false));
}

// Sum over each 16-lane row, result in every lane of the row (VALU only).
__device__ __forceinline__ float row_sum16(float x)
{
    x = dpp_add<0x121>(x);   // row_ror:1
    x = dpp_add<0x122>(x);   // row_ror:2
    x = dpp_add<0x124>(x);   // row_ror:4
    x = dpp_add<0x128>(x);   // row_ror:8
    return x;
}

// lane l gets x[l] + x[l^32] — VALU permlane32_swap.
__device__ __forceinline__ float add_xor32(float x)
{
#if __has_builtin(__builtin_amdgcn_permlane32_swap)
    auto r = __builtin_amdgcn_permlane32_swap(
        __float_as_uint(x), __float_as_uint(x), false, false);
    return __uint_as_float(r[0]) + __uint_as_float(r[1]);
#else
    return x + __shfl_xor(x, 32, 64);
#endif
}

// lane l gets x[l] + x[l^16] — VALU permlane16_swap.
__device__ __forceinline__ float add_xor16(float x)
{
#if __has_builtin(__builtin_amdgcn_permlane16_swap)
    auto r = __builtin_amdgcn_permlane16_swap(
        __float_as_uint(x), __float_as_uint(x), false, false);
    return __uint_as_float(r[0]) + __uint_as_float(r[1]);
#else
    return x + __int_as_float(__builtin_amdgcn_ds_swizzle(__float_as_int(x), 0x401F));
#endif
}

// ---------------------------------------------------------------------------
// 5-bit XOR swizzle within one 4096-float W tile (involution; 16-B groups
// contiguous; read-side bank histogram uniform 8/bank -> conflict-free).
// ---------------------------------------------------------------------------
__device__ __forceinline__ int wswz(int f) { return f ^ (((f >> 7) & 31) << 2); }

// Stage one 16 KB W tile global->LDS via DMA (linear dest, pre-swizzled src).
__device__ __forceinline__ void stage_w_tile(const float* __restrict__ wg,
                                             float* __restrict__ wn, int tid)
{
    #pragma unroll
    for (int j = 0; j < 4; j++) {
        const int P = (tid + j * 256) * 4;
        const int g = wswz(P);
        __builtin_amdgcn_global_load_lds(
            (const __attribute__((address_space(1))) void*)(wg + g),
            (__attribute__((address_space(3))) void*)(wn + P),
            16, 0, 0);
    }
}

// ---------------------------------------------------------------------------
// Producer pass (R5-proven body). UHAT=true additionally stores u_hat as fp16
// (wave-contiguous rows per (b,i)) for the fast passes to stream.
// Grid (NIC, NBG) = 512 blocks x 256 thr; tid = o + 32*hh + 64*bq.
// ---------------------------------------------------------------------------
template<int PASS, bool ATOMIC, bool UHAT>
__global__ __launch_bounds__(256)
void pass_kernel(const float* __restrict__ u, const float* __restrict__ w,
                 const float* __restrict__ pv0, const float* __restrict__ pv1,
                 float* __restrict__ out, _Float16* __restrict__ uhat)
{
    __shared__ __align__(16) float Wsh[2][WTILE];   // 2 x 16 KB, linear

    const int tid   = threadIdx.x;
    const int o     = tid & 31;
    const int hh    = (tid >> 5) & 1;
    const int bq    = tid >> 6;           // 0..3
    const int bbase = blockIdx.y * NBB;
    const int i0    = blockIdx.x * IC;
    const int hofs  = hh * 8;
    const int swm   = o << 2;             // read-side XOR (floats), 5-bit
    const int orow  = o * (DD * HH);

    stage_w_tile(w + (size_t)i0 * WTILE, Wsh[0], tid);

    float vsum[NJB][8];
    if (PASS >= 1) {
        #pragma unroll
        for (int jb = 0; jb < NJB; jb++) {
            const int b = bbase + bq * NJB + jb;
            const float* p = pv0 + ((b * OO + o) * HH + hofs);
            float4 a = *(const float4*)p;
            float4 c = *(const float4*)(p + 4);
            vsum[jb][0] = a.x; vsum[jb][1] = a.y; vsum[jb][2] = a.z; vsum[jb][3] = a.w;
            vsum[jb][4] = c.x; vsum[jb][5] = c.y; vsum[jb][6] = c.z; vsum[jb][7] = c.w;
            if (PASS == 2) {
                const float* q = pv1 + ((b * OO + o) * HH + hofs);
                float4 a2 = *(const float4*)q;
                float4 c2 = *(const float4*)(q + 4);
                vsum[jb][0] += a2.x; vsum[jb][1] += a2.y; vsum[jb][2] += a2.z; vsum[jb][3] += a2.w;
                vsum[jb][4] += c2.x; vsum[jb][5] += c2.y; vsum[jb][6] += c2.z; vsum[jb][7] += c2.w;
            }
        }
    }

    float sacc[NJB][8];
    #pragma unroll
    for (int jb = 0; jb < NJB; jb++)
        #pragma unroll
        for (int h2 = 0; h2 < 8; h2++) sacc[jb][h2] = 0.f;

    __syncthreads();   // drains vmcnt(0): Wsh[0] DMA complete

    for (int ii = 0; ii < IC; ii++) {
        const float* wcur = Wsh[ii & 1];

        if (ii + 1 < IC)
            stage_w_tile(w + (size_t)(i0 + ii + 1) * WTILE, Wsh[(ii + 1) & 1], tid);

        float us[NJB][8];
        #pragma unroll
        for (int jb = 0; jb < NJB; jb++) {
            const float* ub = u + ((size_t)(bbase + bq * NJB + jb) * II + (i0 + ii)) * DD;
            float4 a = *(const float4*)ub;
            float4 c = *(const float4*)(ub + 4);
            us[jb][0] = a.x; us[jb][1] = a.y; us[jb][2] = a.z; us[jb][3] = a.w;
            us[jb][4] = c.x; us[jb][5] = c.y; us[jb][6] = c.z; us[jb][7] = c.w;
        }

        float uh[NJB][8];
        #pragma unroll
        for (int jb = 0; jb < NJB; jb++)
            #pragma unroll
            for (int h2 = 0; h2 < 8; h2++) uh[jb][h2] = 0.f;
        #pragma unroll
        for (int d = 0; d < DD; d++) {
            const int ba  = (d * HH + hofs    ) ^ swm;
            const int bb2 = (d * HH + hofs + 4) ^ swm;
            float4 wa = *(const float4*)&wcur[orow + ba];
            float4 wb = *(const float4*)&wcur[orow + bb2];
            const float wv[8] = {wa.x, wa.y, wa.z, wa.w, wb.x, wb.y, wb.z, wb.w};
            #pragma unroll
            for (int jb = 0; jb < NJB; jb++)
                #pragma unroll
                for (int h2 = 0; h2 < 8; h2++)
                    uh[jb][h2] = fmaf(us[jb][d], wv[h2], uh[jb][h2]);
        }

        // Store u_hat (fp16): wave-contiguous rows, overlaps next DMA.
        if (UHAT) {
            #pragma unroll
            for (int jb = 0; jb < NJB; jb++) {
                const int b = bbase + bq * NJB + jb;
                half8 hv;
                #pragma unroll
                for (int h2 = 0; h2 < 8; h2++) hv[h2] = (_Float16)uh[jb][h2];
                *(half8*)(uhat + (((size_t)b * II + (i0 + ii)) * OO + o) * HH + hofs) = hv;
            }
        }

        float cc[NJB];
        if (PASS == 0) {
            #pragma unroll
            for (int jb = 0; jb < NJB; jb++) cc[jb] = 1.0f / 32.0f;
        } else {
            #pragma unroll
            for (int jb = 0; jb < NJB; jb++) {
                float lg = 0.f;
                #pragma unroll
                for (int h2 = 0; h2 < 8; h2++)
                    lg = fmaf(vsum[jb][h2], uh[jb][h2], lg);
                lg = add_xor32(lg);
                const float e = __expf(lg);
                const float se = add_xor16(row_sum16(e));
                cc[jb] = __fdividef(e, se);
            }
        }

        #pragma unroll
        for (int jb = 0; jb < NJB; jb++)
            #pragma unroll
            for (int h2 = 0; h2 < 8; h2++)
                sacc[jb][h2] = fmaf(cc[jb], uh[jb][h2], sacc[jb][h2]);

        __syncthreads();
    }

    #pragma unroll
    for (int jb = 0; jb < NJB; jb++) {
        const int b = bbase + bq * NJB + jb;
        if (ATOMIC) {
            float* p = out + ((b * OO + o) * HH + hofs);
            #pragma unroll
            for (int h2 = 0; h2 < 8; h2++) atomicAdd(p + h2, sacc[jb][h2]);
        } else {
            float* p = out + ((size_t)blockIdx.x * BB + b) * (OO * HH) + o * HH + hofs;
            *(float4*)p       = make_float4(sacc[jb][0], sacc[jb][1], sacc[jb][2], sacc[jb][3]);
            *(float4*)(p + 4) = make_float4(sacc[jb][4], sacc[jb][5], sacc[jb][6], sacc[jb][7]);
        }
    }
}

// ---------------------------------------------------------------------------
// Fast pass v2 (R14): fused previous-slab reduce + u_hat streaming softmax.
// Block = (i-range of 36, one b); wave q owns a 9-i subgroup.
// Prologue: reduce part_prev (NCHP chunks) for THIS b only — q-split + LDS
// tree + squash -> v_prev in registers. PASS 1 writes v0 to global (32
// same-b blocks write identical values, benign); PASS 2 adds loaded v0.
// Body: R12/R13-proven 9-row register prefetch + 9 independent chains.
// Epilogue: 4-wave LDS tree -> 32-chunk part_out slab.
// Grid (NRNG, BB) = 2048 blocks x 256 thr (8 blocks/CU).
// ---------------------------------------------------------------------------
template<int PASS, int NCHP>
__global__ __launch_bounds__(256)
void fast_pass2_kernel(const _Float16* __restrict__ uhat,
                       const float* __restrict__ part_prev,
                       const float* __restrict__ v0g,   // PASS==2 input
                       float* __restrict__ v0out,       // PASS==1 output
                       float* __restrict__ part_out)
{
    __shared__ float4 red[4][64][2];   // 8 KB, reused (prologue tree, i-tree)

    const int tid  = threadIdx.x;
    const int o    = tid & 31;
    const int hh   = (tid >> 5) & 1;
    const int q    = tid >> 6;               // wave = 9-i subgroup
    const int b    = blockIdx.y;
    const int i0   = blockIdx.x * ICR + q * 9;
    const int hofs = hh * 8;
    const int oh   = o + 32 * hh;            // 0..63

    // Issue u_hat prefetch FIRST (independent of the prologue reduce).
    half8 hv[9];
    #pragma unroll
    for (int ii = 0; ii < 9; ii++)
        hv[ii] = *(const half8*)
            (uhat + (((size_t)b * II + (i0 + ii)) * OO + o) * HH + hofs);

    // ---- prologue: reduce part_prev for this b -> v_prev (replaces a
    //      standalone reduce dispatch; slab is L2/L3-hot) ----
    constexpr int CPQ = NCHP / 4;            // chunks per wave
    float pa[8];
    #pragma unroll
    for (int h2 = 0; h2 < 8; h2++) pa[h2] = 0.f;
    #pragma unroll
    for (int k = 0; k < CPQ; k++) {
        const float* pp = part_prev
            + ((size_t)(q * CPQ + k) * BB + b) * (OO * HH) + o * HH + hofs;
        float4 x = *(const float4*)pp;
        float4 y = *(const float4*)(pp + 4);
        pa[0] += x.x; pa[1] += x.y; pa[2] += x.z; pa[3] += x.w;
        pa[4] += y.x; pa[5] += y.y; pa[6] += y.z; pa[7] += y.w;
    }
    red[q][oh][0] = make_float4(pa[0], pa[1], pa[2], pa[3]);
    red[q][oh][1] = make_float4(pa[4], pa[5], pa[6], pa[7]);
    __syncthreads();

    float s8[8];
    {
        float4 a = red[0][oh][0], c = red[0][oh][1];
        #pragma unroll
        for (int j = 1; j < 4; j++) {
            float4 x = red[j][oh][0], y = red[j][oh][1];
            a.x += x.x; a.y += x.y; a.z += x.z; a.w += x.w;
            c.x += y.x; c.y += y.y; c.z += y.z; c.w += y.w;
        }
        s8[0] = a.x; s8[1] = a.y; s8[2] = a.z; s8[3] = a.w;
        s8[4] = c.x; s8[5] = c.y; s8[6] = c.z; s8[7] = c.w;
    }
    __syncthreads();   // red reuse guard (i-tree writes come later)

    // squash: sq over all 16 h = own 8 + other hh-half (lane ^ 32).
    float sq = 0.f;
    #pragma unroll
    for (int h2 = 0; h2 < 8; h2++) sq = fmaf(s8[h2], s8[h2], sq);
    sq = add_xor32(sq);
    const float scl = (sq / (1.f + sq)) * rsqrtf(sq + 1e-8f);

    float vsum[8];
    #pragma unroll
    for (int h2 = 0; h2 < 8; h2++) vsum[h2] = s8[h2] * scl;

    if (PASS == 1) {
        // Publish v0 for pass 2 (redundant identical writes across blocks).
        if (q == 0) {
            float* p = v0out + ((b * OO + o) * HH + hofs);
            *(float4*)p       = make_float4(vsum[0], vsum[1], vsum[2], vsum[3]);
            *(float4*)(p + 4) = make_float4(vsum[4], vsum[5], vsum[6], vsum[7]);
        }
    } else {
        // vsum = v0 + v1.
        const float* p = v0g + ((b * OO + o) * HH + hofs);
        float4 a = *(const float4*)p;
        float4 c = *(const float4*)(p + 4);
        vsum[0] += a.x; vsum[1] += a.y; vsum[2] += a.z; vsum[3] += a.w;
        vsum[4] += c.x; vsum[5] += c.y; vsum[6] += c.z; vsum[7] += c.w;
    }

    // ---- body: 9 independent softmax chains (R12/R13-proven) ----
    float sacc[8];
    #pragma unroll
    for (int h2 = 0; h2 < 8; h2++) sacc[h2] = 0.f;

    #pragma unroll
    for (int ii = 0; ii < 9; ii++) {
        float uh[8];
        #pragma unroll
        for (int h2 = 0; h2 < 8; h2++) uh[h2] = (float)hv[ii][h2];

        float lg = 0.f;
        #pragma unroll
        for (int h2 = 0; h2 < 8; h2++)
            lg = fmaf(vsum[h2], uh[h2], lg);
        lg = add_xor32(lg);                    // h-half combine (VALU)
        const float e = __expf(lg);
        const float se = add_xor16(row_sum16(e));  // sum over 32 o-lanes
        const float cc = __fdividef(e, se);

        #pragma unroll
        for (int h2 = 0; h2 < 8; h2++)
            sacc[h2] = fmaf(cc, uh[h2], sacc[h2]);
    }

    // ---- epilogue: in-block sum over the 4 waves -> 32-chunk slab ----
    red[q][oh][0] = make_float4(sacc[0], sacc[1], sacc[2], sacc[3]);
    red[q][oh][1] = make_float4(sacc[4], sacc[5], sacc[6], sacc[7]);
    __syncthreads();

    if (tid < 64) {   // one thread per (o,hh)
        float4 a = red[0][tid][0], c = red[0][tid][1];
        #pragma unroll
        for (int j = 1; j < 4; j++) {
            float4 x = red[j][tid][0], y = red[j][tid][1];
            a.x += x.x; a.y += x.y; a.z += x.z; a.w += x.w;
            c.x += y.x; c.y += y.y; c.z += y.z; c.w += y.w;
        }
        float* p = part_out + ((size_t)blockIdx.x * BB + b) * (OO * HH)
                 + (tid & 31) * HH + (tid >> 5) * 8;
        *(float4*)p       = a;
        *(float4*)(p + 4) = c;
    }
}

// ---------------------------------------------------------------------------
// Final reduce-over-chunks + squash (templated chunk count): 256 blocks.
// ---------------------------------------------------------------------------
template<int NCH>
__global__ __launch_bounds__(256)
void reduce_squash_wide_kernel(const float* __restrict__ part, float* __restrict__ v)
{
    const int t4l = threadIdx.x & 31;
    const int icp = threadIdx.x >> 5;
    const int t4  = blockIdx.x * 32 + t4l;

    const float4* p = (const float4*)part + t4;
    float4 acc = make_float4(0.f, 0.f, 0.f, 0.f);
    #pragma unroll
    for (int k = 0; k < NCH / 8; k++) {
        float4 x = p[(size_t)(icp * (NCH / 8) + k) * (BOH / 4)];
        acc.x += x.x; acc.y += x.y; acc.z += x.z; acc.w += x.w;
    }

    __shared__ float4 red[8][32];
    red[icp][t4l] = acc;
    __syncthreads();

    if (threadIdx.x < 32) {
        float4 a = red[0][t4l];
        #pragma unroll
        for (int j = 1; j < 8; j++) {
            float4 x = red[j][t4l];
            a.x += x.x; a.y += x.y; a.z += x.z; a.w += x.w;
        }
        float sq = a.x * a.x + a.y * a.y + a.z * a.z + a.w * a.w;
        sq = dpp_add<0xB1>(sq);   // quad_perm [1,0,3,2]
        sq = dpp_add<0x4E>(sq);   // quad_perm [2,3,0,1]
        const float scale = (sq / (1.f + sq)) * rsqrtf(sq + 1e-8f);
        a.x *= scale; a.y *= scale; a.z *= scale; a.w *= scale;
        ((float4*)v)[t4] = a;
    }
}

// Standalone squash for the atomic tiny-ws fallback.
__global__ __launch_bounds__(256)
void squash_kernel(const float* __restrict__ s, float* __restrict__ v)
{
    const int t = blockIdx.x * blockDim.x + threadIdx.x;
    if (t >= BB * OO) return;
    const float4* sp = (const float4*)(s + t * HH);
    float4 a = sp[0], b = sp[1], c = sp[2], d = sp[3];
    float sq = a.x*a.x + a.y*a.y + a.z*a.z + a.w*a.w
             + b.x*b.x + b.y*b.y + b.z*b.z + b.w*b.w
             + c.x*c.x + c.y*c.y + c.z*c.z + c.w*c.w
             + d.x*d.x + d.y*d.y + d.z*d.z + d.w*d.w;
    const float scale = (sq / (1.f + sq)) * rsqrtf(sq + 1e-8f);
    a.x *= scale; a.y *= scale; a.z *= scale; a.w *= scale;
    b.x *= scale; b.y *= scale; b.z *= scale; b.w *= scale;
    c.x *= scale; c.y *= scale; c.z *= scale; c.w *= scale;
    d.x *= scale; d.y *= scale; d.z *= scale; d.w *= scale;
    float4* vp = (float4*)(v + t * HH);
    vp[0] = a; vp[1] = b; vp[2] = c; vp[3] = d;
}

extern "C" void kernel_launch(void* const* d_in, const int* in_sizes, int n_in,
                              void* d_out, int out_size, void* d_ws, size_t ws_size,
                              hipStream_t stream)
{
    (void)in_sizes; (void)n_in; (void)out_size;
    const float* u = (const float*)d_in[0];
    const float* w = (const float*)d_in[1];
    float* out = (float*)d_out;

    const size_t part0N = (size_t)NIC * BOH;    // 16.8 MB
    const size_t part1N = (size_t)NRNG * BOH;   // 4.2 MB
    const size_t need   = (part0N + 2 * part1N + BOH) * sizeof(float)
                        + UHN * sizeof(_Float16);   // ~101 MB
    const dim3 blk(256);

    if (ws_size >= need) {
        // 4 dispatches: producer -> fast1 (fused reduce0) -> fast2 (fused
        // reduce1) -> final reduce. Each removed dispatch saves a ~6 us gap.
        float* part0    = (float*)d_ws;
        float* part1    = part0 + part0N;
        float* part2    = part1 + part1N;
        float* v0       = part2 + part1N;
        _Float16* uhat  = (_Float16*)(v0 + BOH);
        const int rblocks = BOH / 4 / 32;       // 256 blocks

        pass_kernel<0, false, true><<<dim3(NIC, NBG), blk, 0, stream>>>(
            u, w, nullptr, nullptr, part0, uhat);
        fast_pass2_kernel<1, NIC><<<dim3(NRNG, BB), blk, 0, stream>>>(
            uhat, part0, nullptr, v0, part1);
        fast_pass2_kernel<2, NRNG><<<dim3(NRNG, BB), blk, 0, stream>>>(
            uhat, part1, v0, nullptr, part2);
        reduce_squash_wide_kernel<NRNG><<<rblocks, 256, 0, stream>>>(part2, out);
    } else {
        // Tiny-ws fallback: R5-exact atomic path.
        float* s0 = (float*)d_ws;
        float* s1 = s0 + BOH;
        float* v0 = s1 + BOH;
        float* v1 = v0 + BOH;
        hipMemsetAsync(d_ws, 0, 2 * BOH * sizeof(float), stream);
        hipMemsetAsync(d_out, 0, BOH * sizeof(float), stream);
        const dim3 grid(NIC, NBG);
        const int sq_blocks = (BB * OO + 255) / 256;

        pass_kernel<0, true, false><<<grid, blk, 0, stream>>>(u, w, nullptr, nullptr, s0, nullptr);
        squash_kernel<<<sq_blocks, 256, 0, stream>>>(s0, v0);
        pass_kernel<1, true, false><<<grid, blk, 0, stream>>>(u, w, v0, nullptr, s1, nullptr);
        squash_kernel<<<sq_blocks, 256, 0, stream>>>(s1, v1);
        pass_kernel<2, true, false><<<grid, blk, 0, stream>>>(u, w, v0, v1, out, nullptr);
        squash_kernel<<<sq_blocks, 256, 0, stream>>>(out, out);
    }
}

// Round 15
// 125.734 us; speedup vs baseline: 1.3289x; 1.3289x over previous
//
#include <hip/hip_runtime.h>

// Problem constants
#define BB 64
#define II 1152
#define OO 32
#define DD 8
#define HH 16
#define BOH (BB * OO * HH)    // 32768
#define WTILE (OO * DD * HH)  // 4096 floats per i

// Producer / fallback decomposition (R5-exact): NIC * IC == II, 512 blocks.
#define IC   9
#define NIC  128
#define NBB  16    // b per block
#define NBG  4     // b-groups
#define NJB  4     // b per thread

// Fast-pass decomposition (R13-proven): grid (NRNG, BB) = 2048 blocks; block
// owns (i-range of 36, one b); wave q handles a 9-i subgroup (register
// prefetch + 9 independent softmax chains); 4-wave LDS tree -> 32-chunk slab.
// R14's fused-reduce variant REVERTED: its per-block slab re-read x32
// redundancy = 512 MB logical / 167 MB HBM = +35 us/pass (counter-proven).
#define NRNG 32
#define ICR  (II / NRNG)   // 36

typedef _Float16 half8 __attribute__((ext_vector_type(8)));

// u_hat element count (fp16): 75.5 MB
#define UHN ((size_t)BB * II * OO * HH)

// ---------------------------------------------------------------------------
// DPP add helper (ctrl must be an ICE -> template param).
// ---------------------------------------------------------------------------
template<int CTRL>
__device__ __forceinline__ float dpp_add(float x)
{
    return x + __int_as_float(__builtin_amdgcn_update_dpp(
            0, __float_as_int(x), CTRL, 0xF, 0xF, false));
}

// Sum over each 16-lane row, result in every lane of the row (VALU only).
__device__ __forceinline__ float row_sum16(float x)
{
    x = dpp_add<0x121>(x);   // row_ror:1
    x = dpp_add<0x122>(x);   // row_ror:2
    x = dpp_add<0x124>(x);   // row_ror:4
    x = dpp_add<0x128>(x);   // row_ror:8
    return x;
}

// lane l gets x[l] + x[l^32] — VALU permlane32_swap.
__device__ __forceinline__ float add_xor32(float x)
{
#if __has_builtin(__builtin_amdgcn_permlane32_swap)
    auto r = __builtin_amdgcn_permlane32_swap(
        __float_as_uint(x), __float_as_uint(x), false, false);
    return __uint_as_float(r[0]) + __uint_as_float(r[1]);
#else
    return x + __shfl_xor(x, 32, 64);
#endif
}

// lane l gets x[l] + x[l^16] — VALU permlane16_swap.
__device__ __forceinline__ float add_xor16(float x)
{
#if __has_builtin(__builtin_amdgcn_permlane16_swap)
    auto r = __builtin_amdgcn_permlane16_swap(
        __float_as_uint(x), __float_as_uint(x), false, false);
    return __uint_as_float(r[0]) + __uint_as_float(r[1]);
#else
    return x + __int_as_float(__builtin_amdgcn_ds_swizzle(__float_as_int(x), 0x401F));
#endif
}

// ---------------------------------------------------------------------------
// 5-bit XOR swizzle within one 4096-float W tile (involution; 16-B groups
// contiguous; read-side bank histogram uniform 8/bank -> conflict-free).
// ---------------------------------------------------------------------------
__device__ __forceinline__ int wswz(int f) { return f ^ (((f >> 7) & 31) << 2); }

// Stage one 16 KB W tile global->LDS via DMA (linear dest, pre-swizzled src).
__device__ __forceinline__ void stage_w_tile(const float* __restrict__ wg,
                                             float* __restrict__ wn, int tid)
{
    #pragma unroll
    for (int j = 0; j < 4; j++) {
        const int P = (tid + j * 256) * 4;
        const int g = wswz(P);
        __builtin_amdgcn_global_load_lds(
            (const __attribute__((address_space(1))) void*)(wg + g),
            (__attribute__((address_space(3))) void*)(wn + P),
            16, 0, 0);
    }
}

// ---------------------------------------------------------------------------
// Producer pass (R5-proven body). UHAT=true additionally stores u_hat as fp16
// (wave-contiguous rows per (b,i)) for the fast passes to stream. u_hat
// stores are NON-TEMPORAL (R15): 75.5 MB streamed once, no intra-kernel
// reuse -> don't evict W tiles / partials from L2.
// Grid (NIC, NBG) = 512 blocks x 256 thr; tid = o + 32*hh + 64*bq.
// ---------------------------------------------------------------------------
template<int PASS, bool ATOMIC, bool UHAT>
__global__ __launch_bounds__(256)
void pass_kernel(const float* __restrict__ u, const float* __restrict__ w,
                 const float* __restrict__ pv0, const float* __restrict__ pv1,
                 float* __restrict__ out, _Float16* __restrict__ uhat)
{
    __shared__ __align__(16) float Wsh[2][WTILE];   // 2 x 16 KB, linear

    const int tid   = threadIdx.x;
    const int o     = tid & 31;
    const int hh    = (tid >> 5) & 1;
    const int bq    = tid >> 6;           // 0..3
    const int bbase = blockIdx.y * NBB;
    const int i0    = blockIdx.x * IC;
    const int hofs  = hh * 8;
    const int swm   = o << 2;             // read-side XOR (floats), 5-bit
    const int orow  = o * (DD * HH);

    stage_w_tile(w + (size_t)i0 * WTILE, Wsh[0], tid);

    float vsum[NJB][8];
    if (PASS >= 1) {
        #pragma unroll
        for (int jb = 0; jb < NJB; jb++) {
            const int b = bbase + bq * NJB + jb;
            const float* p = pv0 + ((b * OO + o) * HH + hofs);
            float4 a = *(const float4*)p;
            float4 c = *(const float4*)(p + 4);
            vsum[jb][0] = a.x; vsum[jb][1] = a.y; vsum[jb][2] = a.z; vsum[jb][3] = a.w;
            vsum[jb][4] = c.x; vsum[jb][5] = c.y; vsum[jb][6] = c.z; vsum[jb][7] = c.w;
            if (PASS == 2) {
                const float* q = pv1 + ((b * OO + o) * HH + hofs);
                float4 a2 = *(const float4*)q;
                float4 c2 = *(const float4*)(q + 4);
                vsum[jb][0] += a2.x; vsum[jb][1] += a2.y; vsum[jb][2] += a2.z; vsum[jb][3] += a2.w;
                vsum[jb][4] += c2.x; vsum[jb][5] += c2.y; vsum[jb][6] += c2.z; vsum[jb][7] += c2.w;
            }
        }
    }

    float sacc[NJB][8];
    #pragma unroll
    for (int jb = 0; jb < NJB; jb++)
        #pragma unroll
        for (int h2 = 0; h2 < 8; h2++) sacc[jb][h2] = 0.f;

    __syncthreads();   // drains vmcnt(0): Wsh[0] DMA complete

    for (int ii = 0; ii < IC; ii++) {
        const float* wcur = Wsh[ii & 1];

        if (ii + 1 < IC)
            stage_w_tile(w + (size_t)(i0 + ii + 1) * WTILE, Wsh[(ii + 1) & 1], tid);

        float us[NJB][8];
        #pragma unroll
        for (int jb = 0; jb < NJB; jb++) {
            const float* ub = u + ((size_t)(bbase + bq * NJB + jb) * II + (i0 + ii)) * DD;
            float4 a = *(const float4*)ub;
            float4 c = *(const float4*)(ub + 4);
            us[jb][0] = a.x; us[jb][1] = a.y; us[jb][2] = a.z; us[jb][3] = a.w;
            us[jb][4] = c.x; us[jb][5] = c.y; us[jb][6] = c.z; us[jb][7] = c.w;
        }

        float uh[NJB][8];
        #pragma unroll
        for (int jb = 0; jb < NJB; jb++)
            #pragma unroll
            for (int h2 = 0; h2 < 8; h2++) uh[jb][h2] = 0.f;
        #pragma unroll
        for (int d = 0; d < DD; d++) {
            const int ba  = (d * HH + hofs    ) ^ swm;
            const int bb2 = (d * HH + hofs + 4) ^ swm;
            float4 wa = *(const float4*)&wcur[orow + ba];
            float4 wb = *(const float4*)&wcur[orow + bb2];
            const float wv[8] = {wa.x, wa.y, wa.z, wa.w, wb.x, wb.y, wb.z, wb.w};
            #pragma unroll
            for (int jb = 0; jb < NJB; jb++)
                #pragma unroll
                for (int h2 = 0; h2 < 8; h2++)
                    uh[jb][h2] = fmaf(us[jb][d], wv[h2], uh[jb][h2]);
        }

        // Store u_hat (fp16, NON-TEMPORAL): wave-contiguous rows.
        if (UHAT) {
            #pragma unroll
            for (int jb = 0; jb < NJB; jb++) {
                const int b = bbase + bq * NJB + jb;
                half8 hv;
                #pragma unroll
                for (int h2 = 0; h2 < 8; h2++) hv[h2] = (_Float16)uh[jb][h2];
                __builtin_nontemporal_store(hv,
                    (half8*)(uhat + (((size_t)b * II + (i0 + ii)) * OO + o) * HH + hofs));
            }
        }

        float cc[NJB];
        if (PASS == 0) {
            #pragma unroll
            for (int jb = 0; jb < NJB; jb++) cc[jb] = 1.0f / 32.0f;
        } else {
            #pragma unroll
            for (int jb = 0; jb < NJB; jb++) {
                float lg = 0.f;
                #pragma unroll
                for (int h2 = 0; h2 < 8; h2++)
                    lg = fmaf(vsum[jb][h2], uh[jb][h2], lg);
                lg = add_xor32(lg);
                const float e = __expf(lg);
                const float se = add_xor16(row_sum16(e));
                cc[jb] = __fdividef(e, se);
            }
        }

        #pragma unroll
        for (int jb = 0; jb < NJB; jb++)
            #pragma unroll
            for (int h2 = 0; h2 < 8; h2++)
                sacc[jb][h2] = fmaf(cc[jb], uh[jb][h2], sacc[jb][h2]);

        __syncthreads();
    }

    #pragma unroll
    for (int jb = 0; jb < NJB; jb++) {
        const int b = bbase + bq * NJB + jb;
        if (ATOMIC) {
            float* p = out + ((b * OO + o) * HH + hofs);
            #pragma unroll
            for (int h2 = 0; h2 < 8; h2++) atomicAdd(p + h2, sacc[jb][h2]);
        } else {
            float* p = out + ((size_t)blockIdx.x * BB + b) * (OO * HH) + o * HH + hofs;
            *(float4*)p       = make_float4(sacc[jb][0], sacc[jb][1], sacc[jb][2], sacc[jb][3]);
            *(float4*)(p + 4) = make_float4(sacc[jb][4], sacc[jb][5], sacc[jb][6], sacc[jb][7]);
        }
    }
}

// ---------------------------------------------------------------------------
// Fast pass (R13-proven): streams precomputed fp16 u_hat (NON-TEMPORAL loads:
// 75.5 MB > L2, no reuse within the kernel). Block = (i-range of 36, one b);
// wave q owns a 9-i subgroup (9 rows prefetched to registers, 9 independent
// softmax chains). 4-wave LDS tree -> 32-chunk slab (4.2 MB).
// Grid (NRNG, BB) = 2048 blocks x 256 thr (8 blocks/CU).
// ---------------------------------------------------------------------------
template<int PASS>
__global__ __launch_bounds__(256)
void fast_pass_kernel(const _Float16* __restrict__ uhat,
                      const float* __restrict__ pv0, const float* __restrict__ pv1,
                      float* __restrict__ part)
{
    __shared__ float4 red[4][64][2];   // 8 KB

    const int tid  = threadIdx.x;
    const int o    = tid & 31;
    const int hh   = (tid >> 5) & 1;
    const int q    = tid >> 6;               // wave = 9-i subgroup
    const int b    = blockIdx.y;
    const int i0   = blockIdx.x * ICR + q * 9;
    const int hofs = hh * 8;

    // Prefetch all 9 u_hat rows into registers (independent loads, hoisted).
    half8 hv[9];
    #pragma unroll
    for (int ii = 0; ii < 9; ii++)
        hv[ii] = __builtin_nontemporal_load((const half8*)
            (uhat + (((size_t)b * II + (i0 + ii)) * OO + o) * HH + hofs));

    // vsum (loads overlap the u_hat prefetch window).
    float vsum[8];
    {
        const float* p = pv0 + ((b * OO + o) * HH + hofs);
        float4 a = *(const float4*)p;
        float4 c = *(const float4*)(p + 4);
        vsum[0] = a.x; vsum[1] = a.y; vsum[2] = a.z; vsum[3] = a.w;
        vsum[4] = c.x; vsum[5] = c.y; vsum[6] = c.z; vsum[7] = c.w;
        if (PASS == 2) {
            const float* qq = pv1 + ((b * OO + o) * HH + hofs);
            float4 a2 = *(const float4*)qq;
            float4 c2 = *(const float4*)(qq + 4);
            vsum[0] += a2.x; vsum[1] += a2.y; vsum[2] += a2.z; vsum[3] += a2.w;
            vsum[4] += c2.x; vsum[5] += c2.y; vsum[6] += c2.z; vsum[7] += c2.w;
        }
    }

    float sacc[8];
    #pragma unroll
    for (int h2 = 0; h2 < 8; h2++) sacc[h2] = 0.f;

    // 9 independent softmax chains (scheduler interleaves them).
    #pragma unroll
    for (int ii = 0; ii < 9; ii++) {
        float uh[8];
        #pragma unroll
        for (int h2 = 0; h2 < 8; h2++) uh[h2] = (float)hv[ii][h2];

        float lg = 0.f;
        #pragma unroll
        for (int h2 = 0; h2 < 8; h2++)
            lg = fmaf(vsum[h2], uh[h2], lg);
        lg = add_xor32(lg);                    // h-half combine (VALU)
        const float e = __expf(lg);
        const float se = add_xor16(row_sum16(e));  // sum over 32 o-lanes
        const float cc = __fdividef(e, se);

        #pragma unroll
        for (int h2 = 0; h2 < 8; h2++)
            sacc[h2] = fmaf(cc, uh[h2], sacc[h2]);
    }

    // In-block sum over the 4 waves' 9-i subgroups (LDS tree).
    red[q][o + 32 * hh][0] = make_float4(sacc[0], sacc[1], sacc[2], sacc[3]);
    red[q][o + 32 * hh][1] = make_float4(sacc[4], sacc[5], sacc[6], sacc[7]);
    __syncthreads();

    if (tid < 64) {   // one thread per (o,hh); o = tid&31, hh = tid>>5
        float4 a = red[0][tid][0], c = red[0][tid][1];
        #pragma unroll
        for (int j = 1; j < 4; j++) {
            float4 x = red[j][tid][0], y = red[j][tid][1];
            a.x += x.x; a.y += x.y; a.z += x.z; a.w += x.w;
            c.x += y.x; c.y += y.y; c.z += y.z; c.w += y.w;
        }
        float* p = part + ((size_t)blockIdx.x * BB + b) * (OO * HH)
                 + (tid & 31) * HH + (tid >> 5) * 8;
        *(float4*)p       = a;
        *(float4*)(p + 4) = c;
    }
}

// ---------------------------------------------------------------------------
// Fused reduce-over-chunks + squash, templated on chunk count.
// 256 blocks; block handles 32 consecutive float4 elements of [b][o][h];
// NCH chunks split 8-ways (icp), LDS tree combines, quad-DPP squash.
// ---------------------------------------------------------------------------
template<int NCH>
__global__ __launch_bounds__(256)
void reduce_squash_wide_kernel(const float* __restrict__ part, float* __restrict__ v)
{
    const int t4l = threadIdx.x & 31;
    const int icp = threadIdx.x >> 5;
    const int t4  = blockIdx.x * 32 + t4l;

    const float4* p = (const float4*)part + t4;
    float4 acc = make_float4(0.f, 0.f, 0.f, 0.f);
    #pragma unroll
    for (int k = 0; k < NCH / 8; k++) {
        float4 x = p[(size_t)(icp * (NCH / 8) + k) * (BOH / 4)];
        acc.x += x.x; acc.y += x.y; acc.z += x.z; acc.w += x.w;
    }

    __shared__ float4 red[8][32];
    red[icp][t4l] = acc;
    __syncthreads();

    if (threadIdx.x < 32) {
        float4 a = red[0][t4l];
        #pragma unroll
        for (int j = 1; j < 8; j++) {
            float4 x = red[j][t4l];
            a.x += x.x; a.y += x.y; a.z += x.z; a.w += x.w;
        }
        float sq = a.x * a.x + a.y * a.y + a.z * a.z + a.w * a.w;
        sq = dpp_add<0xB1>(sq);   // quad_perm [1,0,3,2]
        sq = dpp_add<0x4E>(sq);   // quad_perm [2,3,0,1]
        const float scale = (sq / (1.f + sq)) * rsqrtf(sq + 1e-8f);
        a.x *= scale; a.y *= scale; a.z *= scale; a.w *= scale;
        ((float4*)v)[t4] = a;
    }
}

// Standalone squash for the atomic tiny-ws fallback.
__global__ __launch_bounds__(256)
void squash_kernel(const float* __restrict__ s, float* __restrict__ v)
{
    const int t = blockIdx.x * blockDim.x + threadIdx.x;
    if (t >= BB * OO) return;
    const float4* sp = (const float4*)(s + t * HH);
    float4 a = sp[0], b = sp[1], c = sp[2], d = sp[3];
    float sq = a.x*a.x + a.y*a.y + a.z*a.z + a.w*a.w
             + b.x*b.x + b.y*b.y + b.z*b.z + b.w*b.w
             + c.x*c.x + c.y*c.y + c.z*c.z + c.w*c.w
             + d.x*d.x + d.y*d.y + d.z*d.z + d.w*d.w;
    const float scale = (sq / (1.f + sq)) * rsqrtf(sq + 1e-8f);
    a.x *= scale; a.y *= scale; a.z *= scale; a.w *= scale;
    b.x *= scale; b.y *= scale; b.z *= scale; b.w *= scale;
    c.x *= scale; c.y *= scale; c.z *= scale; c.w *= scale;
    d.x *= scale; d.y *= scale; d.z *= scale; d.w *= scale;
    float4* vp = (float4*)(v + t * HH);
    vp[0] = a; vp[1] = b; vp[2] = c; vp[3] = d;
}

extern "C" void kernel_launch(void* const* d_in, const int* in_sizes, int n_in,
                              void* d_out, int out_size, void* d_ws, size_t ws_size,
                              hipStream_t stream)
{
    (void)in_sizes; (void)n_in; (void)out_size;
    const float* u = (const float*)d_in[0];
    const float* w = (const float*)d_in[1];
    float* out = (float*)d_out;

    const size_t partN = (size_t)NIC * BOH;   // sized for the 128-chunk producer slab
    const size_t need  = (partN + 2 * BOH) * sizeof(float) + UHN * sizeof(_Float16);
    const dim3 blk(256);

    if (ws_size >= need) {
        // 6 dispatches (R13-proven): producer pass 0 (writes fp16 u_hat) +
        // 2 streaming passes (in-block i-reduction -> 32-chunk slab) + 3 reduces.
        float* part     = (float*)d_ws;
        float* v0       = part + partN;
        float* v1       = v0 + BOH;
        _Float16* uhat  = (_Float16*)(v1 + BOH);    // 16-B aligned offset
        const int rblocks = BOH / 4 / 32;           // 256 blocks

        pass_kernel<0, false, true><<<dim3(NIC, NBG), blk, 0, stream>>>(
            u, w, nullptr, nullptr, part, uhat);
        reduce_squash_wide_kernel<NIC><<<rblocks, 256, 0, stream>>>(part, v0);
        fast_pass_kernel<1><<<dim3(NRNG, BB), blk, 0, stream>>>(uhat, v0, nullptr, part);
        reduce_squash_wide_kernel<NRNG><<<rblocks, 256, 0, stream>>>(part, v1);
        fast_pass_kernel<2><<<dim3(NRNG, BB), blk, 0, stream>>>(uhat, v0, v1, part);
        reduce_squash_wide_kernel<NRNG><<<rblocks, 256, 0, stream>>>(part, out);
    } else {
        // Tiny-ws fallback: R5-exact atomic path.
        float* s0 = (float*)d_ws;
        float* s1 = s0 + BOH;
        float* v0 = s1 + BOH;
        float* v1 = v0 + BOH;
        hipMemsetAsync(d_ws, 0, 2 * BOH * sizeof(float), stream);
        hipMemsetAsync(d_out, 0, BOH * sizeof(float), stream);
        const dim3 grid(NIC, NBG);
        const int sq_blocks = (BB * OO + 255) / 256;

        pass_kernel<0, true, false><<<grid, blk, 0, stream>>>(u, w, nullptr, nullptr, s0, nullptr);
        squash_kernel<<<sq_blocks, 256, 0, stream>>>(s0, v0);
        pass_kernel<1, true, false><<<grid, blk, 0, stream>>>(u, w, v0, nullptr, s1, nullptr);
        squash_kernel<<<sq_blocks, 256, 0, stream>>>(s1, v1);
        pass_kernel<2, true, false><<<grid, blk, 0, stream>>>(u, w, v0, v1, out, nullptr);
        squash_kernel<<<sq_blocks, 256, 0, stream>>>(out, out);
    }
}

// Round 16
// 120.321 us; speedup vs baseline: 1.3886x; 1.0450x over previous
//
#include <hip/hip_runtime.h>

// Problem constants
#define BB 64
#define II 1152
#define OO 32
#define DD 8
#define HH 16
#define BOH (BB * OO * HH)    // 32768
#define WTILE (OO * DD * HH)  // 4096 floats per i

// Producer / fallback decomposition (R5-exact): NIC * IC == II, 512 blocks.
#define IC   9
#define NIC  128
#define NBB  16    // b per block
#define NBG  4     // b-groups
#define NJB  4     // b per thread

// Fast-pass decomposition (R13-proven): grid (NRNG, BB) = 2048 blocks; block
// owns (i-range of 36, one b); wave q handles a 9-i subgroup (register
// prefetch + 9 independent softmax chains); 4-wave LDS tree -> 32-chunk slab.
// R15's non-temporal hints REVERTED (A/B: +4.6 us — NT loads forfeit L3 hits
// on pass-2's re-read of pass-1-hot u_hat lines).
#define NRNG 32
#define ICR  (II / NRNG)   // 36

typedef _Float16 half8 __attribute__((ext_vector_type(8)));

// u_hat element count (fp16): 75.5 MB
#define UHN ((size_t)BB * II * OO * HH)

// ---------------------------------------------------------------------------
// DPP add helper (ctrl must be an ICE -> template param).
// ---------------------------------------------------------------------------
template<int CTRL>
__device__ __forceinline__ float dpp_add(float x)
{
    return x + __int_as_float(__builtin_amdgcn_update_dpp(
            0, __float_as_int(x), CTRL, 0xF, 0xF, false));
}

// Sum over each 16-lane row, result in every lane of the row (VALU only).
__device__ __forceinline__ float row_sum16(float x)
{
    x = dpp_add<0x121>(x);   // row_ror:1
    x = dpp_add<0x122>(x);   // row_ror:2
    x = dpp_add<0x124>(x);   // row_ror:4
    x = dpp_add<0x128>(x);   // row_ror:8
    return x;
}

// lane l gets x[l] + x[l^32] — VALU permlane32_swap.
__device__ __forceinline__ float add_xor32(float x)
{
#if __has_builtin(__builtin_amdgcn_permlane32_swap)
    auto r = __builtin_amdgcn_permlane32_swap(
        __float_as_uint(x), __float_as_uint(x), false, false);
    return __uint_as_float(r[0]) + __uint_as_float(r[1]);
#else
    return x + __shfl_xor(x, 32, 64);
#endif
}

// lane l gets x[l] + x[l^16] — VALU permlane16_swap.
__device__ __forceinline__ float add_xor16(float x)
{
#if __has_builtin(__builtin_amdgcn_permlane16_swap)
    auto r = __builtin_amdgcn_permlane16_swap(
        __float_as_uint(x), __float_as_uint(x), false, false);
    return __uint_as_float(r[0]) + __uint_as_float(r[1]);
#else
    return x + __int_as_float(__builtin_amdgcn_ds_swizzle(__float_as_int(x), 0x401F));
#endif
}

// ---------------------------------------------------------------------------
// 5-bit XOR swizzle within one 4096-float W tile (involution; 16-B groups
// contiguous; read-side bank histogram uniform 8/bank -> conflict-free).
// ---------------------------------------------------------------------------
__device__ __forceinline__ int wswz(int f) { return f ^ (((f >> 7) & 31) << 2); }

// Stage one 16 KB W tile global->LDS via DMA (linear dest, pre-swizzled src).
__device__ __forceinline__ void stage_w_tile(const float* __restrict__ wg,
                                             float* __restrict__ wn, int tid)
{
    #pragma unroll
    for (int j = 0; j < 4; j++) {
        const int P = (tid + j * 256) * 4;
        const int g = wswz(P);
        __builtin_amdgcn_global_load_lds(
            (const __attribute__((address_space(1))) void*)(wg + g),
            (__attribute__((address_space(3))) void*)(wn + P),
            16, 0, 0);
    }
}

// ---------------------------------------------------------------------------
// Producer pass (R5-proven body). UHAT=true additionally stores u_hat as fp16
// (wave-contiguous rows per (b,i)) for the fast passes to stream.
// Grid (NIC, NBG) = 512 blocks x 256 thr; tid = o + 32*hh + 64*bq.
// ---------------------------------------------------------------------------
template<int PASS, bool ATOMIC, bool UHAT>
__global__ __launch_bounds__(256)
void pass_kernel(const float* __restrict__ u, const float* __restrict__ w,
                 const float* __restrict__ pv0, const float* __restrict__ pv1,
                 float* __restrict__ out, _Float16* __restrict__ uhat)
{
    __shared__ __align__(16) float Wsh[2][WTILE];   // 2 x 16 KB, linear

    const int tid   = threadIdx.x;
    const int o     = tid & 31;
    const int hh    = (tid >> 5) & 1;
    const int bq    = tid >> 6;           // 0..3
    const int bbase = blockIdx.y * NBB;
    const int i0    = blockIdx.x * IC;
    const int hofs  = hh * 8;
    const int swm   = o << 2;             // read-side XOR (floats), 5-bit
    const int orow  = o * (DD * HH);

    stage_w_tile(w + (size_t)i0 * WTILE, Wsh[0], tid);

    float vsum[NJB][8];
    if (PASS >= 1) {
        #pragma unroll
        for (int jb = 0; jb < NJB; jb++) {
            const int b = bbase + bq * NJB + jb;
            const float* p = pv0 + ((b * OO + o) * HH + hofs);
            float4 a = *(const float4*)p;
            float4 c = *(const float4*)(p + 4);
            vsum[jb][0] = a.x; vsum[jb][1] = a.y; vsum[jb][2] = a.z; vsum[jb][3] = a.w;
            vsum[jb][4] = c.x; vsum[jb][5] = c.y; vsum[jb][6] = c.z; vsum[jb][7] = c.w;
            if (PASS == 2) {
                const float* q = pv1 + ((b * OO + o) * HH + hofs);
                float4 a2 = *(const float4*)q;
                float4 c2 = *(const float4*)(q + 4);
                vsum[jb][0] += a2.x; vsum[jb][1] += a2.y; vsum[jb][2] += a2.z; vsum[jb][3] += a2.w;
                vsum[jb][4] += c2.x; vsum[jb][5] += c2.y; vsum[jb][6] += c2.z; vsum[jb][7] += c2.w;
            }
        }
    }

    float sacc[NJB][8];
    #pragma unroll
    for (int jb = 0; jb < NJB; jb++)
        #pragma unroll
        for (int h2 = 0; h2 < 8; h2++) sacc[jb][h2] = 0.f;

    __syncthreads();   // drains vmcnt(0): Wsh[0] DMA complete

    for (int ii = 0; ii < IC; ii++) {
        const float* wcur = Wsh[ii & 1];

        if (ii + 1 < IC)
            stage_w_tile(w + (size_t)(i0 + ii + 1) * WTILE, Wsh[(ii + 1) & 1], tid);

        float us[NJB][8];
        #pragma unroll
        for (int jb = 0; jb < NJB; jb++) {
            const float* ub = u + ((size_t)(bbase + bq * NJB + jb) * II + (i0 + ii)) * DD;
            float4 a = *(const float4*)ub;
            float4 c = *(const float4*)(ub + 4);
            us[jb][0] = a.x; us[jb][1] = a.y; us[jb][2] = a.z; us[jb][3] = a.w;
            us[jb][4] = c.x; us[jb][5] = c.y; us[jb][6] = c.z; us[jb][7] = c.w;
        }

        float uh[NJB][8];
        #pragma unroll
        for (int jb = 0; jb < NJB; jb++)
            #pragma unroll
            for (int h2 = 0; h2 < 8; h2++) uh[jb][h2] = 0.f;
        #pragma unroll
        for (int d = 0; d < DD; d++) {
            const int ba  = (d * HH + hofs    ) ^ swm;
            const int bb2 = (d * HH + hofs + 4) ^ swm;
            float4 wa = *(const float4*)&wcur[orow + ba];
            float4 wb = *(const float4*)&wcur[orow + bb2];
            const float wv[8] = {wa.x, wa.y, wa.z, wa.w, wb.x, wb.y, wb.z, wb.w};
            #pragma unroll
            for (int jb = 0; jb < NJB; jb++)
                #pragma unroll
                for (int h2 = 0; h2 < 8; h2++)
                    uh[jb][h2] = fmaf(us[jb][d], wv[h2], uh[jb][h2]);
        }

        // Store u_hat (fp16): wave-contiguous rows, overlaps next DMA.
        if (UHAT) {
            #pragma unroll
            for (int jb = 0; jb < NJB; jb++) {
                const int b = bbase + bq * NJB + jb;
                half8 hv;
                #pragma unroll
                for (int h2 = 0; h2 < 8; h2++) hv[h2] = (_Float16)uh[jb][h2];
                *(half8*)(uhat + (((size_t)b * II + (i0 + ii)) * OO + o) * HH + hofs) = hv;
            }
        }

        float cc[NJB];
        if (PASS == 0) {
            #pragma unroll
            for (int jb = 0; jb < NJB; jb++) cc[jb] = 1.0f / 32.0f;
        } else {
            #pragma unroll
            for (int jb = 0; jb < NJB; jb++) {
                float lg = 0.f;
                #pragma unroll
                for (int h2 = 0; h2 < 8; h2++)
                    lg = fmaf(vsum[jb][h2], uh[jb][h2], lg);
                lg = add_xor32(lg);
                const float e = __expf(lg);
                const float se = add_xor16(row_sum16(e));
                cc[jb] = __fdividef(e, se);
            }
        }

        #pragma unroll
        for (int jb = 0; jb < NJB; jb++)
            #pragma unroll
            for (int h2 = 0; h2 < 8; h2++)
                sacc[jb][h2] = fmaf(cc[jb], uh[jb][h2], sacc[jb][h2]);

        __syncthreads();
    }

    #pragma unroll
    for (int jb = 0; jb < NJB; jb++) {
        const int b = bbase + bq * NJB + jb;
        if (ATOMIC) {
            float* p = out + ((b * OO + o) * HH + hofs);
            #pragma unroll
            for (int h2 = 0; h2 < 8; h2++) atomicAdd(p + h2, sacc[jb][h2]);
        } else {
            float* p = out + ((size_t)blockIdx.x * BB + b) * (OO * HH) + o * HH + hofs;
            *(float4*)p       = make_float4(sacc[jb][0], sacc[jb][1], sacc[jb][2], sacc[jb][3]);
            *(float4*)(p + 4) = make_float4(sacc[jb][4], sacc[jb][5], sacc[jb][6], sacc[jb][7]);
        }
    }
}

// ---------------------------------------------------------------------------
// Fast pass (R13-proven): streams precomputed fp16 u_hat. Block = (i-range
// of 36, one b); wave q owns a 9-i subgroup (9 rows prefetched to registers,
// 9 independent softmax chains). 4-wave LDS tree -> 32-chunk slab (4.2 MB).
// Grid (NRNG, BB) = 2048 blocks x 256 thr (8 blocks/CU).
// ---------------------------------------------------------------------------
template<int PASS>
__global__ __launch_bounds__(256)
void fast_pass_kernel(const _Float16* __restrict__ uhat,
                      const float* __restrict__ pv0, const float* __restrict__ pv1,
                      float* __restrict__ part)
{
    __shared__ float4 red[4][64][2];   // 8 KB

    const int tid  = threadIdx.x;
    const int o    = tid & 31;
    const int hh   = (tid >> 5) & 1;
    const int q    = tid >> 6;               // wave = 9-i subgroup
    const int b    = blockIdx.y;
    const int i0   = blockIdx.x * ICR + q * 9;
    const int hofs = hh * 8;

    // Prefetch all 9 u_hat rows into registers (independent loads, hoisted).
    half8 hv[9];
    #pragma unroll
    for (int ii = 0; ii < 9; ii++)
        hv[ii] = *(const half8*)
            (uhat + (((size_t)b * II + (i0 + ii)) * OO + o) * HH + hofs);

    // vsum (loads overlap the u_hat prefetch window).
    float vsum[8];
    {
        const float* p = pv0 + ((b * OO + o) * HH + hofs);
        float4 a = *(const float4*)p;
        float4 c = *(const float4*)(p + 4);
        vsum[0] = a.x; vsum[1] = a.y; vsum[2] = a.z; vsum[3] = a.w;
        vsum[4] = c.x; vsum[5] = c.y; vsum[6] = c.z; vsum[7] = c.w;
        if (PASS == 2) {
            const float* qq = pv1 + ((b * OO + o) * HH + hofs);
            float4 a2 = *(const float4*)qq;
            float4 c2 = *(const float4*)(qq + 4);
            vsum[0] += a2.x; vsum[1] += a2.y; vsum[2] += a2.z; vsum[3] += a2.w;
            vsum[4] += c2.x; vsum[5] += c2.y; vsum[6] += c2.z; vsum[7] += c2.w;
        }
    }

    float sacc[8];
    #pragma unroll
    for (int h2 = 0; h2 < 8; h2++) sacc[h2] = 0.f;

    // 9 independent softmax chains (scheduler interleaves them).
    #pragma unroll
    for (int ii = 0; ii < 9; ii++) {
        float uh[8];
        #pragma unroll
        for (int h2 = 0; h2 < 8; h2++) uh[h2] = (float)hv[ii][h2];

        float lg = 0.f;
        #pragma unroll
        for (int h2 = 0; h2 < 8; h2++)
            lg = fmaf(vsum[h2], uh[h2], lg);
        lg = add_xor32(lg);                    // h-half combine (VALU)
        const float e = __expf(lg);
        const float se = add_xor16(row_sum16(e));  // sum over 32 o-lanes
        const float cc = __fdividef(e, se);

        #pragma unroll
        for (int h2 = 0; h2 < 8; h2++)
            sacc[h2] = fmaf(cc, uh[h2], sacc[h2]);
    }

    // In-block sum over the 4 waves' 9-i subgroups (LDS tree).
    red[q][o + 32 * hh][0] = make_float4(sacc[0], sacc[1], sacc[2], sacc[3]);
    red[q][o + 32 * hh][1] = make_float4(sacc[4], sacc[5], sacc[6], sacc[7]);
    __syncthreads();

    if (tid < 64) {   // one thread per (o,hh); o = tid&31, hh = tid>>5
        float4 a = red[0][tid][0], c = red[0][tid][1];
        #pragma unroll
        for (int j = 1; j < 4; j++) {
            float4 x = red[j][tid][0], y = red[j][tid][1];
            a.x += x.x; a.y += x.y; a.z += x.z; a.w += x.w;
            c.x += y.x; c.y += y.y; c.z += y.z; c.w += y.w;
        }
        float* p = part + ((size_t)blockIdx.x * BB + b) * (OO * HH)
                 + (tid & 31) * HH + (tid >> 5) * 8;
        *(float4*)p       = a;
        *(float4*)(p + 4) = c;
    }
}

// ---------------------------------------------------------------------------
// Fused reduce-over-chunks + squash, templated on chunk count.
// 256 blocks; block handles 32 consecutive float4 elements of [b][o][h];
// NCH chunks split 8-ways (icp), LDS tree combines, quad-DPP squash.
// ---------------------------------------------------------------------------
template<int NCH>
__global__ __launch_bounds__(256)
void reduce_squash_wide_kernel(const float* __restrict__ part, float* __restrict__ v)
{
    const int t4l = threadIdx.x & 31;
    const int icp = threadIdx.x >> 5;
    const int t4  = blockIdx.x * 32 + t4l;

    const float4* p = (const float4*)part + t4;
    float4 acc = make_float4(0.f, 0.f, 0.f, 0.f);
    #pragma unroll
    for (int k = 0; k < NCH / 8; k++) {
        float4 x = p[(size_t)(icp * (NCH / 8) + k) * (BOH / 4)];
        acc.x += x.x; acc.y += x.y; acc.z += x.z; acc.w += x.w;
    }

    __shared__ float4 red[8][32];
    red[icp][t4l] = acc;
    __syncthreads();

    if (threadIdx.x < 32) {
        float4 a = red[0][t4l];
        #pragma unroll
        for (int j = 1; j < 8; j++) {
            float4 x = red[j][t4l];
            a.x += x.x; a.y += x.y; a.z += x.z; a.w += x.w;
        }
        float sq = a.x * a.x + a.y * a.y + a.z * a.z + a.w * a.w;
        sq = dpp_add<0xB1>(sq);   // quad_perm [1,0,3,2]
        sq = dpp_add<0x4E>(sq);   // quad_perm [2,3,0,1]
        const float scale = (sq / (1.f + sq)) * rsqrtf(sq + 1e-8f);
        a.x *= scale; a.y *= scale; a.z *= scale; a.w *= scale;
        ((float4*)v)[t4] = a;
    }
}

// Standalone squash for the atomic tiny-ws fallback.
__global__ __launch_bounds__(256)
void squash_kernel(const float* __restrict__ s, float* __restrict__ v)
{
    const int t = blockIdx.x * blockDim.x + threadIdx.x;
    if (t >= BB * OO) return;
    const float4* sp = (const float4*)(s + t * HH);
    float4 a = sp[0], b = sp[1], c = sp[2], d = sp[3];
    float sq = a.x*a.x + a.y*a.y + a.z*a.z + a.w*a.w
             + b.x*b.x + b.y*b.y + b.z*b.z + b.w*b.w
             + c.x*c.x + c.y*c.y + c.z*c.z + c.w*c.w
             + d.x*d.x + d.y*d.y + d.z*d.z + d.w*d.w;
    const float scale = (sq / (1.f + sq)) * rsqrtf(sq + 1e-8f);
    a.x *= scale; a.y *= scale; a.z *= scale; a.w *= scale;
    b.x *= scale; b.y *= scale; b.z *= scale; b.w *= scale;
    c.x *= scale; c.y *= scale; c.z *= scale; c.w *= scale;
    d.x *= scale; d.y *= scale; d.z *= scale; d.w *= scale;
    float4* vp = (float4*)(v + t * HH);
    vp[0] = a; vp[1] = b; vp[2] = c; vp[3] = d;
}

extern "C" void kernel_launch(void* const* d_in, const int* in_sizes, int n_in,
                              void* d_out, int out_size, void* d_ws, size_t ws_size,
                              hipStream_t stream)
{
    (void)in_sizes; (void)n_in; (void)out_size;
    const float* u = (const float*)d_in[0];
    const float* w = (const float*)d_in[1];
    float* out = (float*)d_out;

    const size_t partN = (size_t)NIC * BOH;   // sized for the 128-chunk producer slab
    const size_t need  = (partN + 2 * BOH) * sizeof(float) + UHN * sizeof(_Float16);
    const dim3 blk(256);

    if (ws_size >= need) {
        // 6 dispatches (R13-proven): producer pass 0 (writes fp16 u_hat) +
        // 2 streaming passes (in-block i-reduction -> 32-chunk slab) + 3 reduces.
        float* part     = (float*)d_ws;
        float* v0       = part + partN;
        float* v1       = v0 + BOH;
        _Float16* uhat  = (_Float16*)(v1 + BOH);    // 16-B aligned offset
        const int rblocks = BOH / 4 / 32;           // 256 blocks

        pass_kernel<0, false, true><<<dim3(NIC, NBG), blk, 0, stream>>>(
            u, w, nullptr, nullptr, part, uhat);
        reduce_squash_wide_kernel<NIC><<<rblocks, 256, 0, stream>>>(part, v0);
        fast_pass_kernel<1><<<dim3(NRNG, BB), blk, 0, stream>>>(uhat, v0, nullptr, part);
        reduce_squash_wide_kernel<NRNG><<<rblocks, 256, 0, stream>>>(part, v1);
        fast_pass_kernel<2><<<dim3(NRNG, BB), blk, 0, stream>>>(uhat, v0, v1, part);
        reduce_squash_wide_kernel<NRNG><<<rblocks, 256, 0, stream>>>(part, out);
    } else {
        // Tiny-ws fallback: R5-exact atomic path.
        float* s0 = (float*)d_ws;
        float* s1 = s0 + BOH;
        float* v0 = s1 + BOH;
        float* v1 = v0 + BOH;
        hipMemsetAsync(d_ws, 0, 2 * BOH * sizeof(float), stream);
        hipMemsetAsync(d_out, 0, BOH * sizeof(float), stream);
        const dim3 grid(NIC, NBG);
        const int sq_blocks = (BB * OO + 255) / 256;

        pass_kernel<0, true, false><<<grid, blk, 0, stream>>>(u, w, nullptr, nullptr, s0, nullptr);
        squash_kernel<<<sq_blocks, 256, 0, stream>>>(s0, v0);
        pass_kernel<1, true, false><<<grid, blk, 0, stream>>>(u, w, v0, nullptr, s1, nullptr);
        squash_kernel<<<sq_blocks, 256, 0, stream>>>(s1, v1);
        pass_kernel<2, true, false><<<grid, blk, 0, stream>>>(u, w, v0, v1, out, nullptr);
        squash_kernel<<<sq_blocks, 256, 0, stream>>>(out, out);
    }
}